// Round 11
// 1581.123 us; speedup vs baseline: 1.0352x; 1.0352x over previous
//
#include <hip/hip_runtime.h>
#include <hip/hip_bf16.h>

// MoE layer: T=16384 tokens, D=1024, F=4096, E=16 experts, top-2, capacity 2560.
// GEMMs: 256x128 tile, BK=64, 8 waves (64x64/wave, acc[4][4]=64 VGPR -> no spill),
// 3-slot LDS ring (144 KiB), stage-2-ahead with counted vmcnt(6) per K-tile (T4),
// explicit lgkmcnt(0)+sched_barrier(0) per phase (m201 template), setprio (T5),
// BK64 XOR swizzle (conflict-free ds_read_b128). Race-free by construction:
// slot write-issue at iter k is separated from its last read (iter k-1) by the
// boundary barrier AND every wave's explicit lgkmcnt(0).

#define T_TOK 16384
#define DDIM  1024
#define FDIM  4096
#define NEXP  16
#define TOPK  2
#define CAP   2560              // ceil(2*16384/16 * 1.25)
#define TK    (T_TOK*TOPK)      // 32768

typedef float  floatx4 __attribute__((ext_vector_type(4)));
typedef __bf16 bf16x8  __attribute__((ext_vector_type(8)));

__device__ __forceinline__ unsigned short f2b(float f) {
  union { float f; unsigned int u; } v; v.f = f;
  unsigned int r = (v.u + 0x7FFFu + ((v.u >> 16) & 1u)) >> 16;  // RNE
  return (unsigned short)r;
}

// jax.nn.gelu default (approximate=True, tanh form); tanh via exp.
__device__ __forceinline__ float gelu_tanh(float x) {
  float u = 1.5957691216057308f * (x + 0.044715f * x * x * x);
  float eu = __expf(u);
  float t = 1.0f - 2.0f / (eu + 1.0f);
  return 0.5f * x * (1.0f + t);
}

// ---------------- gating: one wave per token ----------------
__global__ void gating_kernel(const float* __restrict__ x, const float* __restrict__ gw,
                              int* __restrict__ topi, float* __restrict__ topv) {
  int gid  = blockIdx.x * blockDim.x + threadIdx.x;
  int tok  = gid >> 6;
  int lane = gid & 63;
  const float* xr = x + (size_t)tok * DDIM;
  float acc[NEXP];
#pragma unroll
  for (int e = 0; e < NEXP; ++e) acc[e] = 0.f;
  for (int j = 0; j < DDIM / 64; ++j) {
    int d = j * 64 + lane;
    float xv = xr[d];
    const float4* g4 = (const float4*)(gw + (size_t)d * NEXP);
    float gv[NEXP];
    *(float4*)&gv[0]  = g4[0];
    *(float4*)&gv[4]  = g4[1];
    *(float4*)&gv[8]  = g4[2];
    *(float4*)&gv[12] = g4[3];
#pragma unroll
    for (int e = 0; e < NEXP; ++e) acc[e] += xv * gv[e];
  }
#pragma unroll
  for (int s = 32; s > 0; s >>= 1) {
#pragma unroll
    for (int e = 0; e < NEXP; ++e) acc[e] += __shfl_xor(acc[e], s, 64);
  }
  if (lane == 0) {
    int i1 = 0; float v1 = acc[0];
#pragma unroll
    for (int e = 1; e < NEXP; ++e) if (acc[e] > v1) { v1 = acc[e]; i1 = e; }
    int i2 = -1; float v2 = -1e30f;
#pragma unroll
    for (int e = 0; e < NEXP; ++e) if (e != i1 && acc[e] > v2) { v2 = acc[e]; i2 = e; }
    float r = __expf(v2 - v1);
    float g1v = 1.0f / (1.0f + r);
    topi[2 * tok] = i1;  topi[2 * tok + 1] = i2;
    topv[2 * tok] = g1v; topv[2 * tok + 1] = 1.0f - g1v;
  }
}

// ---------------- scan: token-major per-expert positions (single block, 512 thr) ----------------
__global__ void scan_kernel(const int* __restrict__ topi,
                            int* __restrict__ slot, int* __restrict__ cnt) {
  __shared__ int lcnt[512][17];      // stride 17 ints: conflict-free
  const int PER = TK / 512;          // 64
  int tid = threadIdx.x;
  int base = tid * PER;
  int c[NEXP];
#pragma unroll
  for (int e = 0; e < NEXP; ++e) c[e] = 0;
  for (int i = 0; i < PER; i += 4) {
    int4 v = *(const int4*)(topi + base + i);
#pragma unroll
    for (int e = 0; e < NEXP; ++e)
      c[e] += (v.x == e) + (v.y == e) + (v.z == e) + (v.w == e);
  }
#pragma unroll
  for (int e = 0; e < NEXP; ++e) lcnt[tid][e] = c[e];
  __syncthreads();
  if (tid < NEXP) {
    int run = 0;
    for (int j = 0; j < 512; ++j) { int t = lcnt[j][tid]; lcnt[j][tid] = run; run += t; }
    cnt[tid] = run < CAP ? run : CAP;
  }
  __syncthreads();
#pragma unroll
  for (int e = 0; e < NEXP; ++e) c[e] = lcnt[tid][e];
  for (int i = 0; i < PER; ++i) {
    int ev = topi[base + i];
    int p = 0;
#pragma unroll
    for (int e = 0; e < NEXP; ++e) { p += (ev == e) ? c[e] : 0; c[e] += (ev == e); }
    slot[base + i] = (p < CAP) ? ev * CAP + p : -1;
  }
}

// ---------------- scatter x -> xe (bf16); 4 slots per 256-thread block ----------------
__global__ void scatter_kernel(const float* __restrict__ x, const int* __restrict__ slot,
                               unsigned short* __restrict__ xe) {
  int i = blockIdx.x * 4 + (threadIdx.x >> 6);
  int s = slot[i];
  if (s < 0) return;
  const float* src = x + (size_t)(i >> 1) * DDIM;
  unsigned short* dst = xe + (size_t)s * DDIM;
  int lane = threadIdx.x & 63;
#pragma unroll
  for (int j = 0; j < 4; ++j) {
    int idx = j * 256 + lane * 4;
    float4 v = *(const float4*)(src + idx);
    ushort4 o;
    o.x = f2b(v.x); o.y = f2b(v.y); o.z = f2b(v.z); o.w = f2b(v.w);
    *(ushort4*)(dst + idx) = o;
  }
}

// ---------------- transpose+convert: fp32 [e][R][Cc] -> bf16 [e][Cc][R] ----------------
__global__ void transpose_kernel(const float* __restrict__ src, unsigned short* __restrict__ dst,
                                 int R, int Cc) {
  __shared__ __align__(16) float tile[64][65];
  int e = blockIdx.z;
  const float* S = src + (size_t)e * R * Cc;
  unsigned short* Dp = dst + (size_t)e * R * Cc;
  int c0 = blockIdx.x * 64;
  int r0 = blockIdx.y * 64;
  int tr  = threadIdx.x >> 4;        // 0..15
  int tc4 = (threadIdx.x & 15) * 4;  // 0..60
#pragma unroll
  for (int p = 0; p < 4; ++p) {
    int r = p * 16 + tr;
    float4 v = *(const float4*)(S + (size_t)(r0 + r) * Cc + c0 + tc4);
    *(float4*)&tile[r][tc4] = v;
  }
  __syncthreads();
#pragma unroll
  for (int p = 0; p < 4; ++p) {
    int oc = p * 16 + tr;            // output row (c-dim)
    ushort4 o;
    o.x = f2b(tile[tc4 + 0][oc]);
    o.y = f2b(tile[tc4 + 1][oc]);
    o.z = f2b(tile[tc4 + 2][oc]);
    o.w = f2b(tile[tc4 + 3][oc]);
    *(ushort4*)(Dp + (size_t)(c0 + oc) * R + r0 + tc4) = o;
  }
}

// ---------------- MFMA GEMM: 256x128 tile, BK=64, 8 waves, 3-slot LDS ring ----------------
__device__ __forceinline__ void glds16(const void* g, void* l) {
  __builtin_amdgcn_global_load_lds((const __attribute__((address_space(1))) void*)g,
                                   (__attribute__((address_space(3))) void*)l, 16, 0, 0);
}

// MODE 0: h = gelu(A@B^T + b1) stored bf16.  MODE 1: ye = A@B^T + b2 stored fp32.
// SWZ  1: within expert, n-panels of 2 with full m-sweep inner (A-panel L2 reuse).
// Slot layout (48KB): A [256 rows][128B] as 4x 8KB units | B [128][128B] as 2x 8KB units.
// Swizzle: 16B chunk at row r, chunk c stored at position (c + (r&7))&7; glds source
// pre-swizzled, ds_read applies the same XOR -> uniform 8-lanes/position (conflict-free).
template<int MODE, int SWZ>
__global__ __launch_bounds__(512, 2) void moe_gemm(
    const unsigned short* __restrict__ A,   // [E][CAP][Kd] bf16
    const unsigned short* __restrict__ Bt,  // [E][Nd][Kd] bf16
    const float* __restrict__ bias,         // [E][Nd]
    unsigned short* __restrict__ Hout,      // MODE0
    float* __restrict__ Ye,                 // MODE1
    const int* __restrict__ cnt,
    int Kd, int Nd, int nbx, int nby)
{
  extern __shared__ __align__(16) char smem[];   // 3 slots x 48KB = 144KB
  const int SLOT = 49152;

  int e = blockIdx.z;
  int ccnt = cnt[e];
  int lin = blockIdx.x;
  int bx, by;
  if (SWZ) {
    int p = lin / (nby * 2);
    int r = lin - p * (nby * 2);
    by = r >> 1;
    bx = p * 2 + (r & 1);
  } else {
    bx = lin % nbx;
    by = lin / nbx;
  }
  int row0 = by * 256;
  if (row0 >= ccnt) return;                  // per-expert early exit (uniform)
  int n0 = bx * 128;

  int tid  = threadIdx.x;
  int wid  = tid >> 6;        // 0..7
  int lane = tid & 63;
  int quad = lane >> 4;
  int l16  = lane & 15;
  int wm = wid & 3;           // 0..3 -> 64-row band
  int wn = wid >> 2;          // 0..1 -> 64-col band

  const unsigned short* Ae = A  + (size_t)e * CAP * Kd;
  const unsigned short* Be = Bt + (size_t)e * Nd  * Kd;

  // staging: unit = 64 rows x 64 cols bf16 = 8KB = 1 glds16/thread.
  // LDS linear dest (wid*1024 + lane*16) <-> row_in_unit = wid*8 + (lane>>3),
  // position = lane&7. Stored position p holds chunk (p - (r&7))&7 ->
  // source chunk = ((lane&7) - ((lane>>3)&7)) & 7.
  int srow   = wid * 8 + (lane >> 3);
  int schunk = ((lane & 7) - ((lane >> 3) & 7)) & 7;
  const char* gA = (const char*)(Ae + (size_t)(row0 + srow) * Kd) + schunk * 16;
  const char* gB = (const char*)(Be + (size_t)(n0  + srow) * Kd) + schunk * 16;
  size_t ustep = (size_t)64 * Kd * 2;        // bytes between units (64 rows)
  int ldwid = wid * 1024;

  // fragment read offsets: row ri, chunk c=kk*4+quad at position (c + (ri&7))&7;
  // ri&7 == l16&7 for all fragments (row bases are multiples of 16).
  int c0   = ((quad + (l16 & 7)) & 7) * 16;
  int aoff =         (wm * 64 + l16) * 128 + c0;   // kk=1: aoff ^ 64
  int boff = 32768 + (wn * 64 + l16) * 128 + c0;

  floatx4 acc[4][4];
#pragma unroll
  for (int i = 0; i < 4; ++i)
#pragma unroll
    for (int j = 0; j < 4; ++j) acc[i][j] = (floatx4){0.f, 0.f, 0.f, 0.f};

  int nk = Kd >> 6;

  // prologue: stage K-tiles 0,1 (slots 0,1; 6 glds each), wait tile 0 only.
#pragma unroll
  for (int kk = 0; kk < 2; ++kk) {
    char* sb = smem + kk * SLOT;
    const char* a = gA + (size_t)kk * 128;
    const char* b = gB + (size_t)kk * 128;
    glds16(a,             sb +         ldwid);
    glds16(a +     ustep, sb +  8192 + ldwid);
    glds16(a + 2 * ustep, sb + 16384 + ldwid);
    glds16(a + 3 * ustep, sb + 24576 + ldwid);
    glds16(b,             sb + 32768 + ldwid);
    glds16(b +     ustep, sb + 40960 + ldwid);
  }
  asm volatile("s_waitcnt vmcnt(6)" ::: "memory");
  __builtin_amdgcn_s_barrier();

  int cs = 0, sx = 2;
  for (int k = 0; k < nk; ++k) {
    const char* sb = smem + cs * SLOT;          // compute slot (tile k)
    char* ss = smem + sx * SLOT;                // stage slot (tile k+2)
    bool st = (k + 2 < nk);                     // uniform
    const char* a2 = gA + (size_t)(k + 2) * 128;
    const char* b2 = gB + (size_t)(k + 2) * 128;

    bf16x8 af[4], bf[4];
    // ---- phase 0 (kk=0): 8 ds_reads; stage A-u0,A-u1,B-u0 of tile k+2 ----
#pragma unroll
    for (int i = 0; i < 4; ++i) af[i] = *(const bf16x8*)(sb + aoff + i * 2048);
#pragma unroll
    for (int j = 0; j < 4; ++j) bf[j] = *(const bf16x8*)(sb + boff + j * 2048);
    if (st) {
      glds16(a2,         ss +         ldwid);
      glds16(a2 + ustep, ss +  8192 + ldwid);
      glds16(b2,         ss + 32768 + ldwid);
    }
    __builtin_amdgcn_s_barrier();
    asm volatile("s_waitcnt lgkmcnt(0)" ::: "memory");
    __builtin_amdgcn_sched_barrier(0);
    __builtin_amdgcn_s_setprio(1);
#pragma unroll
    for (int i = 0; i < 4; ++i)
#pragma unroll
      for (int j = 0; j < 4; ++j)
        acc[i][j] = __builtin_amdgcn_mfma_f32_16x16x32_bf16(af[i], bf[j], acc[i][j], 0, 0, 0);
    __builtin_amdgcn_s_setprio(0);
    __builtin_amdgcn_s_barrier();
    // ---- phase 1 (kk=1): 8 ds_reads; stage A-u2,A-u3,B-u1; K-tile boundary ----
#pragma unroll
    for (int i = 0; i < 4; ++i) af[i] = *(const bf16x8*)(sb + (aoff ^ 64) + i * 2048);
#pragma unroll
    for (int j = 0; j < 4; ++j) bf[j] = *(const bf16x8*)(sb + (boff ^ 64) + j * 2048);
    if (st) {
      glds16(a2 + 2 * ustep, ss + 16384 + ldwid);
      glds16(a2 + 3 * ustep, ss + 24576 + ldwid);
      glds16(b2 +     ustep, ss + 40960 + ldwid);
    }
    __builtin_amdgcn_s_barrier();
    asm volatile("s_waitcnt lgkmcnt(0)" ::: "memory");
    __builtin_amdgcn_sched_barrier(0);
    __builtin_amdgcn_s_setprio(1);
#pragma unroll
    for (int i = 0; i < 4; ++i)
#pragma unroll
      for (int j = 0; j < 4; ++j)
        acc[i][j] = __builtin_amdgcn_mfma_f32_16x16x32_bf16(af[i], bf[j], acc[i][j], 0, 0, 0);
    __builtin_amdgcn_s_setprio(0);
    if (st) { asm volatile("s_waitcnt vmcnt(6)" ::: "memory"); }  // tile k+1 landed
    else    { asm volatile("s_waitcnt vmcnt(0)" ::: "memory"); }  // tail drain
    __builtin_amdgcn_s_barrier();

    cs = (cs == 2) ? 0 : cs + 1;
    sx = (sx == 2) ? 0 : sx + 1;
  }

  // epilogue: C row = row0 + wm*64 + i*16 + quad*4 + r, col = n0 + wn*64 + j*16 + l16
#pragma unroll
  for (int i = 0; i < 4; ++i) {
    int rbase = row0 + wm * 64 + i * 16 + quad * 4;
#pragma unroll
    for (int j = 0; j < 4; ++j) {
      int col = n0 + wn * 64 + j * 16 + l16;
      float bv = bias[(size_t)e * Nd + col];
#pragma unroll
      for (int r = 0; r < 4; ++r) {
        int rg = rbase + r;
        float v = acc[i][j][r] + bv;
        if (MODE == 0)
          Hout[((size_t)e * CAP + rg) * Nd + col] = f2b(gelu_tanh(v));
        else
          Ye[((size_t)e * CAP + rg) * Nd + col] = v;
      }
    }
  }
}

// ---------------- combine: out[t] = sum_k gate_k * ye[slot_k] ----------------
__global__ void combine_kernel(const float* __restrict__ ye, const int* __restrict__ slot,
                               const float* __restrict__ topv, float* __restrict__ out) {
  int t = blockIdx.x * 4 + (threadIdx.x >> 6);
  int lane = threadIdx.x & 63;
  int s0 = slot[2 * t], s1 = slot[2 * t + 1];
  float g0 = topv[2 * t], g1 = topv[2 * t + 1];
  const float* r0 = ye + (size_t)(s0 < 0 ? 0 : s0) * DDIM;
  const float* r1 = ye + (size_t)(s1 < 0 ? 0 : s1) * DDIM;
  float* o = out + (size_t)t * DDIM;
#pragma unroll
  for (int j = 0; j < 4; ++j) {
    int idx = j * 256 + lane * 4;
    float4 a = (s0 >= 0) ? *(const float4*)(r0 + idx) : (float4){0, 0, 0, 0};
    float4 b = (s1 >= 0) ? *(const float4*)(r1 + idx) : (float4){0, 0, 0, 0};
    float4 w;
    w.x = g0 * a.x + g1 * b.x;
    w.y = g0 * a.y + g1 * b.y;
    w.z = g0 * a.z + g1 * b.z;
    w.w = g0 * a.w + g1 * b.w;
    *(float4*)(o + idx) = w;
  }
}

extern "C" void kernel_launch(void* const* d_in, const int* in_sizes, int n_in,
                              void* d_out, int out_size, void* d_ws, size_t ws_size,
                              hipStream_t stream) {
  const float* x  = (const float*)d_in[0];
  const float* gw = (const float*)d_in[1];
  const float* w1 = (const float*)d_in[2];
  const float* b1 = (const float*)d_in[3];
  const float* w2 = (const float*)d_in[4];
  const float* b2 = (const float*)d_in[5];
  float* out = (float*)d_out;

  char* ws = (char*)d_ws;
  size_t off = 0;
  auto alloc = [&](size_t bytes) -> void* {
    void* p = ws + off;
    off = (off + bytes + 255) & ~(size_t)255;
    return p;
  };
  int*   topi  = (int*)  alloc((size_t)TK * 4);
  float* topv  = (float*)alloc((size_t)TK * 4);
  int*   slot  = (int*)  alloc((size_t)TK * 4);
  int*   cnt   = (int*)  alloc(256);
  unsigned short* xe  = (unsigned short*)alloc((size_t)NEXP * CAP  * DDIM * 2); // 84 MB
  unsigned short* w1t = (unsigned short*)alloc((size_t)NEXP * FDIM * DDIM * 2); // 134 MB
  unsigned short* w2t = (unsigned short*)alloc((size_t)NEXP * DDIM * FDIM * 2); // 134 MB
  unsigned short* h   = (unsigned short*)alloc((size_t)NEXP * CAP  * FDIM * 2); // 336 MB
  // ye (168 MB fp32) aliases xe+w1t (218 MB): both dead once GEMM1 completes.
  float* ye = (float*)xe;
  (void)ws_size; (void)in_sizes; (void)n_in; (void)out_size;

  // raise dynamic-LDS cap to 144 KiB for the ring-buffered GEMMs
  using gemm_fn = void(*)(const unsigned short*, const unsigned short*, const float*,
                          unsigned short*, float*, const int*, int, int, int, int);
  gemm_fn f0 = moe_gemm<0, 1>;
  gemm_fn f1 = moe_gemm<1, 0>;
  hipFuncSetAttribute((const void*)f0, hipFuncAttributeMaxDynamicSharedMemorySize, 147456);
  hipFuncSetAttribute((const void*)f1, hipFuncAttributeMaxDynamicSharedMemorySize, 147456);

  hipLaunchKernelGGL(gating_kernel, dim3(T_TOK / 4), dim3(256), 0, stream, x, gw, topi, topv);
  hipLaunchKernelGGL(scan_kernel, dim3(1), dim3(512), 0, stream, topi, slot, cnt);
  hipLaunchKernelGGL(scatter_kernel, dim3(TK / 4), dim3(256), 0, stream, x, slot, xe);
  hipLaunchKernelGGL(transpose_kernel, dim3(FDIM / 64, DDIM / 64, NEXP), dim3(256), 0, stream,
                     w1, w1t, DDIM, FDIM);
  hipLaunchKernelGGL(transpose_kernel, dim3(DDIM / 64, FDIM / 64, NEXP), dim3(256), 0, stream,
                     w2, w2t, FDIM, DDIM);
  hipLaunchKernelGGL((moe_gemm<0, 1>), dim3((FDIM / 128) * (CAP / 256), 1, NEXP), dim3(512),
                     147456, stream, xe, w1t, b1, h, (float*)nullptr, cnt,
                     DDIM, FDIM, FDIM / 128, CAP / 256);
  hipLaunchKernelGGL((moe_gemm<1, 0>), dim3((DDIM / 128) * (CAP / 256), 1, NEXP), dim3(512),
                     147456, stream, h, w2t, b2, (unsigned short*)nullptr, ye, cnt,
                     FDIM, DDIM, DDIM / 128, CAP / 256);
  hipLaunchKernelGGL(combine_kernel, dim3(T_TOK / 4), dim3(256), 0, stream, ye, slot, topv, out);
}